// Round 9
// baseline (166.052 us; speedup 1.0000x reference)
//
#include <hip/hip_runtime.h>

#define N_EMB   8192
#define D_EMB   128
#define NSTEPS  201
#define NB      128                  // 8192 / 64 tiles per dim
#define TBLOCKS (NB*(NB+1)/2)        // 8256 upper-tri 64x64 tiles incl. diagonal
#define NCOPY   16                   // replicated global pos-histogram copies
#define NHIST   16                   // per-quarter-wave LDS copies
#define PGRID   2048                 // persistent grid (8 blocks/CU)

typedef __attribute__((ext_vector_type(8))) short bf16x8;
typedef __attribute__((ext_vector_type(4))) float f32x4;

// packed per-bin accumulator: (count << 21) | fq, fq = round(frac*1024)
#define CNT_SHIFT  21
#define FRAC_MASK  ((1u << CNT_SHIFT) - 1u)

__device__ __forceinline__ unsigned short f2bf(float f) {
  unsigned int u = __builtin_bit_cast(unsigned int, f);
  u = (u + 0x7fffu + ((u >> 16) & 1u)) >> 16;   // RNE fp32 -> bf16
  return (unsigned short)u;
}

// ---- tile id -> (bi, bj), bi <= bj ----
__device__ __forceinline__ void tile_coords(int t, int& bi, int& bj) {
  int rem = TBLOCKS - 1 - t;
  int r   = (int)((sqrtf(8.0f*(float)rem + 1.0f) - 1.0f) * 0.5f);
  while ((r+1)*(r+2)/2 <= rem) ++r;
  while (r*(r+1)/2 > rem) --r;
  bi = NB - 1 - r;
  bj = NB - 1 - (rem - r*(r+1)/2);
}

// ---- pre-pass: fp32 -> bf16 fragment-tiled; zeroes ghist/accb/tickets ----
__global__ __launch_bounds__(256) void convert_kernel(
    const float* __restrict__ x1, const float* __restrict__ x2,
    unsigned short* __restrict__ x1b, unsigned short* __restrict__ x2b,
    float* __restrict__ ghist, float* __restrict__ accb,
    unsigned int* __restrict__ gdone)
{
  int t = blockIdx.x * 256 + threadIdx.x;
  if (t < NCOPY*NSTEPS) ghist[t] = 0.0f;
  if (t < 64) accb[t] = 0.0f;
  if (t == 64) { gdone[0] = 0u; gdone[1] = 0u; }
  const float*    src = (t < 131072) ? x1  : x2;
  unsigned short* dst = (t < 131072) ? x1b : x2b;
  int tt  = t & 131071;
  int r   = tt >> 4;
  int c16 = tt & 15;
  const float4* g = reinterpret_cast<const float4*>(src + ((size_t)r << 7) + c16*8);
  float4 v0 = g[0], v1 = g[1];
  int R = r >> 4, fr = r & 15, K = c16 >> 2, kg = c16 & 3;
  size_t chunk = ((size_t)(R*4 + K) << 6) + (size_t)(kg*16 + fr);
  uint4 p;
  p.x = f2bf(v0.x) | ((unsigned int)f2bf(v0.y) << 16);
  p.y = f2bf(v0.z) | ((unsigned int)f2bf(v0.w) << 16);
  p.z = f2bf(v1.x) | ((unsigned int)f2bf(v1.y) << 16);
  p.w = f2bf(v1.z) | ((unsigned int)f2bf(v1.w) << 16);
  *reinterpret_cast<uint4*>(dst + chunk*8) = p;
}

// ============ pass B: positive-pair histogram; last block builds interp table ============
__global__ __launch_bounds__(256, 8) void poshist_kernel(
    const unsigned short* __restrict__ x1b, const unsigned short* __restrict__ x2b,
    const float* __restrict__ t1g, const float* __restrict__ t2g,
    float* __restrict__ ghist, unsigned int* __restrict__ gdone,
    float2* __restrict__ pd, float* __restrict__ np_out)
{
  __shared__ unsigned int whist[NHIST][NSTEPS];
  __shared__ float hfin[NSTEPS];
  __shared__ int lastFlag;

  const int tid = threadIdx.x;
  for (int b = tid; b < NHIST*NSTEPS; b += 256) ((unsigned int*)whist)[b] = 0u;

  const int lane = tid & 63;
  const int w    = tid >> 6;
  const int wr   = w >> 1, wc = w & 1;
  const int fr   = lane & 15;
  const int kg   = lane >> 4;
  const int rbase = kg * 4;
  unsigned int* wh = whist[(w << 2) | kg];

  const int t0  = (int)(((long)blockIdx.x       * TBLOCKS) / PGRID);
  const int t1e = (int)(((long)(blockIdx.x + 1) * TBLOCKS) / PGRID);

  __syncthreads();                            // whist zero visible

  for (int t = t0; t < t1e; ++t) {
    int bi, bj; tile_coords(t, bi, bj);
    const int gi0 = bi*64, gj0 = bj*64;
    const bool full = (bi != bj);

    const int Ra = (gi0 >> 4) + wr*2;
    const int Rb = (gj0 >> 4) + wc*2;
    f32x4 acc00 = {0.f,0.f,0.f,0.f}, acc01 = {0.f,0.f,0.f,0.f};
    f32x4 acc10 = {0.f,0.f,0.f,0.f}, acc11 = {0.f,0.f,0.f,0.f};
#pragma unroll
    for (int ks = 0; ks < 4; ++ks) {
      bf16x8 a0 = *reinterpret_cast<const bf16x8*>(x1b + ((((size_t)Ra    *4 + ks)*64 + lane) << 3));
      bf16x8 a1 = *reinterpret_cast<const bf16x8*>(x1b + ((((size_t)(Ra+1)*4 + ks)*64 + lane) << 3));
      bf16x8 b0 = *reinterpret_cast<const bf16x8*>(x2b + ((((size_t)Rb    *4 + ks)*64 + lane) << 3));
      bf16x8 b1 = *reinterpret_cast<const bf16x8*>(x2b + ((((size_t)(Rb+1)*4 + ks)*64 + lane) << 3));
      acc00 = __builtin_amdgcn_mfma_f32_16x16x32_bf16(a0, b0, acc00, 0, 0, 0);
      acc01 = __builtin_amdgcn_mfma_f32_16x16x32_bf16(a0, b1, acc01, 0, 0, 0);
      acc10 = __builtin_amdgcn_mfma_f32_16x16x32_bf16(a1, b0, acc10, 0, 0, 0);
      acc11 = __builtin_amdgcn_mfma_f32_16x16x32_bf16(a1, b1, acc11, 0, 0, 0);
    }

    float T2v[2][4], T1v[2];
#pragma unroll
    for (int tm = 0; tm < 2; ++tm)
#pragma unroll
      for (int rr = 0; rr < 4; ++rr) T2v[tm][rr] = t2g[gi0 + wr*32 + tm*16 + rbase + rr];
    T1v[0] = t1g[gj0 + wc*32 + fr];
    T1v[1] = t1g[gj0 + wc*32 + 16 + fr];

    // C/D layout (m89/m91): col = lane&15, row = (lane>>4)*4 + reg
    auto dep = [&](const f32x4& a, int tm, int tn) {
      const int lj = wc*32 + tn*16 + fr;
      const float t1v = T1v[tn];
#pragma unroll
      for (int rr = 0; rr < 4; ++rr) {
        const int li = wr*32 + tm*16 + rbase + rr;
        bool take = (full || (lj > li)) && (T2v[tm][rr] * t1v > 0.0f);
        float uu = fmaf(a[rr], 102400.0f, 102400.5f);
        int   iu = (int)uu;
        int  idx = iu >> 10;
        idx = idx < 0 ? 0 : (idx > NSTEPS-1 ? NSTEPS-1 : idx);
        unsigned int pk = (1u << CNT_SHIFT) | (unsigned int)(iu & 1023);
        if (take) atomicAdd(&wh[idx], pk);
      }
    };
    dep(acc00, 0, 0); dep(acc01, 0, 1);
    dep(acc10, 1, 0); dep(acc11, 1, 1);
  }
  __syncthreads();

  // unpack + flush: h[b] = cnt[b] - fr[b]/1024 + fr[b-1]/1024 ; h[200] = cnt[200] + fr[199]/1024
  float* gh = ghist + (size_t)(blockIdx.x & (NCOPY-1)) * NSTEPS;
  if (tid < NSTEPS) {
    const int b = tid;
    unsigned int cp = 0; float fp = 0.f, fpm1 = 0.f;
#pragma unroll
    for (int ww = 0; ww < NHIST; ++ww) {
      unsigned int vp = whist[ww][b];
      cp += vp >> CNT_SHIFT;  fp += (float)(vp & FRAC_MASK);
      if (b > 0) fpm1 += (float)(whist[ww][b-1] & FRAC_MASK);
    }
    const float inv = 1.0f / 1024.0f;
    float hv = (b == NSTEPS-1) ? ((float)cp + fpm1 * inv)
                               : ((float)cp - fp * inv + fpm1 * inv);
    if (hv != 0.0f) atomicAdd(&gh[b], hv);
  }

  // ---- ticket: last block builds the affine interp table ----
  if (tid == 0) {
    __threadfence();
    unsigned int prev = atomicAdd(&gdone[0], 1u);
    lastFlag = (prev == (unsigned int)(PGRID - 1));
  }
  __syncthreads();
  if (lastFlag) {
    __threadfence();
    if (tid < NSTEPS) {
      float s = 0.f;
      const volatile float* gv = ghist;
#pragma unroll
      for (int c = 0; c < NCOPY; ++c) s += gv[(size_t)c*NSTEPS + tid];
      hfin[tid] = s;
    }
    __syncthreads();
    if (tid == 0) {
      float C[NSTEPS + 1];
      float run = 0.f;
      for (int b = 0; b < NSTEPS; ++b) { run += hfin[b]; C[b] = run; }
      C[NSTEPS] = run;                     // dC[200] = 0 (idx_hi clamp)
      np_out[0] = run;                     // Np (weights telescope to 1/pair)
      float invn = 1.0f / fmaxf(run, 1.0f);
      for (int b = 0; b < NSTEPS; ++b) {
        float d  = (C[b+1] - C[b]) * invn;
        float cv = C[b] * invn;
        // contrib(s in bin b) = cv + ((s+1)*100 - b)*d = alpha + s*beta
        pd[b] = make_float2(fmaf((float)(100 - b), d, cv), 100.0f * d);
      }
    }
  }
}

// ====== pass D: negative pairs interpolate pos-CDF; last block writes loss ======
__global__ __launch_bounds__(256, 8) void neginterp_kernel(
    const unsigned short* __restrict__ x1b, const unsigned short* __restrict__ x2b,
    const float* __restrict__ t1g, const float* __restrict__ t2g,
    const float2* __restrict__ pd, const float* __restrict__ np_in,
    float* __restrict__ accb, unsigned int* __restrict__ gdone,
    float* __restrict__ out)
{
  __shared__ float2 sPD[NSTEPS];
  __shared__ float wsum[4];
  __shared__ int lastFlag;

  const int tid = threadIdx.x;
  if (tid < NSTEPS) sPD[tid] = pd[tid];

  const int lane = tid & 63;
  const int w    = tid >> 6;
  const int wr   = w >> 1, wc = w & 1;
  const int fr   = lane & 15;
  const int kg   = lane >> 4;
  const int rbase = kg * 4;

  const int t0  = (int)(((long)blockIdx.x       * TBLOCKS) / PGRID);
  const int t1e = (int)(((long)(blockIdx.x + 1) * TBLOCKS) / PGRID);

  __syncthreads();                            // sPD staged

  float acc = 0.0f;

  for (int t = t0; t < t1e; ++t) {
    int bi, bj; tile_coords(t, bi, bj);
    const int gi0 = bi*64, gj0 = bj*64;
    const bool full = (bi != bj);

    const int Ra = (gi0 >> 4) + wr*2;
    const int Rb = (gj0 >> 4) + wc*2;
    f32x4 acc00 = {0.f,0.f,0.f,0.f}, acc01 = {0.f,0.f,0.f,0.f};
    f32x4 acc10 = {0.f,0.f,0.f,0.f}, acc11 = {0.f,0.f,0.f,0.f};
#pragma unroll
    for (int ks = 0; ks < 4; ++ks) {
      bf16x8 a0 = *reinterpret_cast<const bf16x8*>(x1b + ((((size_t)Ra    *4 + ks)*64 + lane) << 3));
      bf16x8 a1 = *reinterpret_cast<const bf16x8*>(x1b + ((((size_t)(Ra+1)*4 + ks)*64 + lane) << 3));
      bf16x8 b0 = *reinterpret_cast<const bf16x8*>(x2b + ((((size_t)Rb    *4 + ks)*64 + lane) << 3));
      bf16x8 b1 = *reinterpret_cast<const bf16x8*>(x2b + ((((size_t)(Rb+1)*4 + ks)*64 + lane) << 3));
      acc00 = __builtin_amdgcn_mfma_f32_16x16x32_bf16(a0, b0, acc00, 0, 0, 0);
      acc01 = __builtin_amdgcn_mfma_f32_16x16x32_bf16(a0, b1, acc01, 0, 0, 0);
      acc10 = __builtin_amdgcn_mfma_f32_16x16x32_bf16(a1, b0, acc10, 0, 0, 0);
      acc11 = __builtin_amdgcn_mfma_f32_16x16x32_bf16(a1, b1, acc11, 0, 0, 0);
    }

    float T2v[2][4], T1v[2];
#pragma unroll
    for (int tm = 0; tm < 2; ++tm)
#pragma unroll
      for (int rr = 0; rr < 4; ++rr) T2v[tm][rr] = t2g[gi0 + wr*32 + tm*16 + rbase + rr];
    T1v[0] = t1g[gj0 + wc*32 + fr];
    T1v[1] = t1g[gj0 + wc*32 + 16 + fr];

    auto evalTile = [&](const f32x4& a, int tm, int tn) {
      const int lj = wc*32 + tn*16 + fr;
      const float t1v = T1v[tn];
#pragma unroll
      for (int rr = 0; rr < 4; ++rr) {
        const int li = wr*32 + tm*16 + rbase + rr;
        float s = a[rr];
        bool take = (full || (lj > li)) && (T2v[tm][rr] * t1v <= 0.0f);
        float uu = fmaf(s, 100.0f, 100.0f);
        int  idx = (int)uu;
        idx = idx < 0 ? 0 : (idx > NSTEPS-1 ? NSTEPS-1 : idx);
        float2 ab = sPD[idx];
        float contrib = fmaf(s, ab.y, ab.x);
        acc += take ? contrib : 0.0f;
      }
    };
    evalTile(acc00, 0, 0); evalTile(acc01, 0, 1);
    evalTile(acc10, 1, 0); evalTile(acc11, 1, 1);
  }

  // block reduction
#pragma unroll
  for (int off = 32; off > 0; off >>= 1) acc += __shfl_xor(acc, off, 64);
  if (lane == 0) wsum[w] = acc;
  __syncthreads();
  if (tid == 0) {
    atomicAdd(&accb[blockIdx.x & 63], wsum[0] + wsum[1] + wsum[2] + wsum[3]);
    __threadfence();
    unsigned int prev = atomicAdd(&gdone[1], 1u);
    lastFlag = (prev == (unsigned int)(PGRID - 1));
  }
  __syncthreads();
  if (lastFlag && tid == 0) {
    __threadfence();
    const volatile float* av = accb;
    float s = 0.f;
    for (int c = 0; c < 64; ++c) s += av[c];
    const float TOT = 33550336.0f;            // N*(N-1)/2
    float nn = fmaxf(TOT - np_in[0], 1.0f);
    out[0] = s / nn;
  }
}

extern "C" void kernel_launch(void* const* d_in, const int* in_sizes, int n_in,
                              void* d_out, int out_size, void* d_ws, size_t ws_size,
                              hipStream_t stream) {
  const float* x1 = (const float*)d_in[0];
  const float* x2 = (const float*)d_in[1];
  const float* t1 = (const float*)d_in[2];
  const float* t2 = (const float*)d_in[3];
  float* out = (float*)d_out;

  const size_t BF_BYTES = (size_t)N_EMB * D_EMB * sizeof(unsigned short);  // 2 MB each
  char* p = (char*)d_ws;
  unsigned short* x1b   = (unsigned short*)p;   p += BF_BYTES;
  unsigned short* x2b   = (unsigned short*)p;   p += BF_BYTES;
  float*          ghist = (float*)p;            p += (size_t)NCOPY*NSTEPS*sizeof(float);
  float*          accb  = (float*)p;            p += 64*sizeof(float);
  float2*         pd    = (float2*)p;           p += (size_t)NSTEPS*sizeof(float2);
  float*          np    = (float*)p;            p += sizeof(float);
  unsigned int*   gdone = (unsigned int*)p;

  convert_kernel<<<(2*N_EMB*D_EMB/8 + 255)/256, 256, 0, stream>>>(x1, x2, x1b, x2b, ghist, accb, gdone);
  poshist_kernel<<<PGRID, 256, 0, stream>>>(x1b, x2b, t1, t2, ghist, gdone, pd, np);
  neginterp_kernel<<<PGRID, 256, 0, stream>>>(x1b, x2b, t1, t2, pd, np, accb, gdone, out);
}

// Round 10
// 75.946 us; speedup vs baseline: 2.1864x; 2.1864x over previous
//
#include <hip/hip_runtime.h>

#define N_EMB   8192
#define D_EMB   128
#define NSTEPS  201
#define NB      128                  // 8192 / 64 tiles per dim
#define TBLOCKS (NB*(NB+1)/2)        // 8256 upper-tri tiles incl. diagonal
#define NCOPY   64                   // replicated global pos-histograms
#define NHIST   16                   // per-quarter-wave LDS histogram copies
#define PGRID   2048                 // persistent grid (8 blocks/CU)

typedef __attribute__((ext_vector_type(8))) short bf16x8;
typedef __attribute__((ext_vector_type(4))) float f32x4;

// packed per-bin accumulator: (count << 21) | fq, fq = round(frac*1024)
#define CNT_SHIFT  21
#define FRAC_MASK  ((1u << CNT_SHIFT) - 1u)
#define NZERO      (NCOPY * NSTEPS)          // ghist floats to zero

__device__ __forceinline__ unsigned short f2bf(float f) {
  unsigned int u = __builtin_bit_cast(unsigned int, f);
  u = (u + 0x7fffu + ((u >> 16) & 1u)) >> 16;   // RNE fp32 -> bf16
  return (unsigned short)u;
}

// ---- tile id -> (bi, bj), bi <= bj ----
__device__ __forceinline__ void tile_coords(int t, int& bi, int& bj) {
  int rem = TBLOCKS - 1 - t;
  int r   = (int)((sqrtf(8.0f*(float)rem + 1.0f) - 1.0f) * 0.5f);
  while ((r+1)*(r+2)/2 <= rem) ++r;
  while (r*(r+1)/2 > rem) --r;
  bi = NB - 1 - r;
  bj = NB - 1 - (rem - r*(r+1)/2);
}

// ---- pre-pass: fp32 -> bf16 fragment-tiled layout; zeroes ghist/accb ----
__global__ __launch_bounds__(256) void convert_kernel(
    const float* __restrict__ x1, const float* __restrict__ x2,
    unsigned short* __restrict__ x1b, unsigned short* __restrict__ x2b,
    float* __restrict__ ghist, float* __restrict__ accb)
{
  int t = blockIdx.x * 256 + threadIdx.x;
  if (t < NZERO) ghist[t] = 0.0f;
  if (t < 64)    accb[t]  = 0.0f;
  const float*    src = (t < 131072) ? x1  : x2;
  unsigned short* dst = (t < 131072) ? x1b : x2b;
  int tt  = t & 131071;
  int r   = tt >> 4;
  int c16 = tt & 15;
  const float4* g = reinterpret_cast<const float4*>(src + ((size_t)r << 7) + c16*8);
  float4 v0 = g[0], v1 = g[1];
  int R = r >> 4, fr = r & 15, K = c16 >> 2, kg = c16 & 3;
  size_t chunk = ((size_t)(R*4 + K) << 6) + (size_t)(kg*16 + fr);
  uint4 p;
  p.x = f2bf(v0.x) | ((unsigned int)f2bf(v0.y) << 16);
  p.y = f2bf(v0.z) | ((unsigned int)f2bf(v0.w) << 16);
  p.z = f2bf(v1.x) | ((unsigned int)f2bf(v1.y) << 16);
  p.w = f2bf(v1.z) | ((unsigned int)f2bf(v1.w) << 16);
  *reinterpret_cast<uint4*>(dst + chunk*8) = p;
}

// ============ pass B: positive-pair histogram (persistent blocks) ============
__global__ __launch_bounds__(256, 8) void poshist_kernel(
    const unsigned short* __restrict__ x1b, const unsigned short* __restrict__ x2b,
    const float* __restrict__ t1, const float* __restrict__ t2,
    float* __restrict__ ghist)
{
  __shared__ float sT1[64], sT2[64];
  __shared__ unsigned int whist[NHIST][NSTEPS];

  const int tid = threadIdx.x;
  for (int b = tid; b < NHIST*NSTEPS; b += 256) ((unsigned int*)whist)[b] = 0u;

  const int lane = tid & 63;
  const int w    = tid >> 6;
  const int wr   = w >> 1, wc = w & 1;
  const int fr   = lane & 15;
  const int kg   = lane >> 4;
  const int rbase = kg * 4;
  unsigned int* wh = whist[(w << 2) | kg];

  const int t0  = (int)(((unsigned)blockIdx.x       * (unsigned)TBLOCKS) >> 11);
  const int t1e = (int)((((unsigned)blockIdx.x + 1u) * (unsigned)TBLOCKS) >> 11);

  for (int t = t0; t < t1e; ++t) {
    int bi, bj; tile_coords(t, bi, bj);
    const int gi0 = bi*64, gj0 = bj*64;
    const bool full = (bi != bj);

    __syncthreads();                         // prev tile epilogue done with sT (covers whist zero)
    if (tid < 64)        sT2[tid]      = t2[gi0 + tid];
    else if (tid < 128)  sT1[tid - 64] = t1[gj0 + (tid - 64)];
    __syncthreads();

    const int Ra = (gi0 >> 4) + wr*2;
    const int Rb = (gj0 >> 4) + wc*2;
    f32x4 acc00 = {0.f,0.f,0.f,0.f}, acc01 = {0.f,0.f,0.f,0.f};
    f32x4 acc10 = {0.f,0.f,0.f,0.f}, acc11 = {0.f,0.f,0.f,0.f};
#pragma unroll
    for (int ks = 0; ks < 4; ++ks) {
      bf16x8 a0 = *reinterpret_cast<const bf16x8*>(x1b + ((((size_t)Ra    *4 + ks)*64 + lane) << 3));
      bf16x8 a1 = *reinterpret_cast<const bf16x8*>(x1b + ((((size_t)(Ra+1)*4 + ks)*64 + lane) << 3));
      bf16x8 b0 = *reinterpret_cast<const bf16x8*>(x2b + ((((size_t)Rb    *4 + ks)*64 + lane) << 3));
      bf16x8 b1 = *reinterpret_cast<const bf16x8*>(x2b + ((((size_t)(Rb+1)*4 + ks)*64 + lane) << 3));
      acc00 = __builtin_amdgcn_mfma_f32_16x16x32_bf16(a0, b0, acc00, 0, 0, 0);
      acc01 = __builtin_amdgcn_mfma_f32_16x16x32_bf16(a0, b1, acc01, 0, 0, 0);
      acc10 = __builtin_amdgcn_mfma_f32_16x16x32_bf16(a1, b0, acc10, 0, 0, 0);
      acc11 = __builtin_amdgcn_mfma_f32_16x16x32_bf16(a1, b1, acc11, 0, 0, 0);
    }

    // hoist target reads (static indices -> registers)
    float T2v[2][4], T1v[2];
#pragma unroll
    for (int tm = 0; tm < 2; ++tm)
#pragma unroll
      for (int rr = 0; rr < 4; ++rr) T2v[tm][rr] = sT2[wr*32 + tm*16 + rbase + rr];
    T1v[0] = sT1[wc*32 + fr];
    T1v[1] = sT1[wc*32 + 16 + fr];

    // C/D layout (m89/m91): col = lane&15, row = (lane>>4)*4 + reg
    auto dep = [&](const f32x4& a, int tm, int tn) {
      const int lj = wc*32 + tn*16 + fr;
      const float t1v = T1v[tn];
#pragma unroll
      for (int rr = 0; rr < 4; ++rr) {
        const int li = wr*32 + tm*16 + rbase + rr;
        bool take = (full || (lj > li)) && (T2v[tm][rr] * t1v > 0.0f);
        float uu = fmaf(a[rr], 102400.0f, 102400.5f);
        int   iu = (int)uu;
        int  idx = iu >> 10;
        idx = idx < 0 ? 0 : (idx > NSTEPS-1 ? NSTEPS-1 : idx);
        unsigned int pk = (1u << CNT_SHIFT) | (unsigned int)(iu & 1023);
        if (take) atomicAdd(&wh[idx], pk);
      }
    };
    dep(acc00, 0, 0); dep(acc01, 0, 1);
    dep(acc10, 1, 0); dep(acc11, 1, 1);
  }
  __syncthreads();

  // unpack + flush once:  h[b] = cnt[b] - fr[b]/1024 + fr[b-1]/1024 ; h[200] = cnt[200] + fr[199]/1024
  float* gh = ghist + (size_t)(blockIdx.x & (NCOPY-1)) * NSTEPS;
  if (tid < NSTEPS) {
    const int b = tid;
    unsigned int cp = 0; float fp = 0.f, fpm1 = 0.f;
#pragma unroll
    for (int ww = 0; ww < NHIST; ++ww) {
      unsigned int vp = whist[ww][b];
      cp += vp >> CNT_SHIFT;  fp += (float)(vp & FRAC_MASK);
      if (b > 0) fpm1 += (float)(whist[ww][b-1] & FRAC_MASK);
    }
    const float inv = 1.0f / 1024.0f;
    float hpv = (b == NSTEPS-1) ? ((float)cp + fpm1 * inv)
                                : ((float)cp - fp * inv + fpm1 * inv);
    if (hpv != 0.0f) atomicAdd(&gh[b], hpv);
  }
}

// ====== pass C: sum copies, cumsum, build affine interp table (alpha, beta) ======
// contrib(s in bin b) = C[b]/Np + ((s+1)*100 - b)*dC[b]/Np = alpha[b] + s*beta[b]
__global__ void cdf_kernel(const float* __restrict__ ghist,
                           float2* __restrict__ pd, float* __restrict__ np_out)
{
  __shared__ float h[NSTEPS];
  __shared__ float C[NSTEPS + 1];
  const int tid = threadIdx.x;
  if (tid < NSTEPS) {
    float s = 0.f;
    for (int c = 0; c < NCOPY; ++c) s += ghist[(size_t)c*NSTEPS + tid];
    h[tid] = s;
  }
  __syncthreads();
  if (tid == 0) {
    float run = 0.f;
    for (int b = 0; b < NSTEPS; ++b) { run += h[b]; C[b] = run; }
    C[NSTEPS] = run;                   // dC[200] = 0 (idx_hi clamp)
    np_out[0] = run;                   // Np (weights telescope to 1/pair)
  }
  __syncthreads();
  if (tid < NSTEPS) {
    float np  = C[NSTEPS - 1];
    float inv = 1.0f / fmaxf(np, 1.0f);
    float d   = (C[tid + 1] - C[tid]) * inv;
    float cv  = C[tid] * inv;
    float alpha = fmaf((float)(100 - tid), d, cv);
    float beta  = 100.0f * d;
    pd[tid] = make_float2(alpha, beta);
  }
}

// ====== pass D: negative pairs interpolate pos-CDF (persistent, register acc) ======
__global__ __launch_bounds__(256, 8) void neginterp_kernel(
    const unsigned short* __restrict__ x1b, const unsigned short* __restrict__ x2b,
    const float* __restrict__ t1, const float* __restrict__ t2,
    const float2* __restrict__ pd, float* __restrict__ accbuf)
{
  __shared__ float sT1[64], sT2[64];
  __shared__ float2 sPD[NSTEPS];
  __shared__ float wsum[4];

  const int tid = threadIdx.x;
  if (tid < NSTEPS) sPD[tid] = pd[tid];

  const int lane = tid & 63;
  const int w    = tid >> 6;
  const int wr   = w >> 1, wc = w & 1;
  const int fr   = lane & 15;
  const int kg   = lane >> 4;
  const int rbase = kg * 4;

  const int t0  = (int)(((unsigned)blockIdx.x       * (unsigned)TBLOCKS) >> 11);
  const int t1e = (int)((((unsigned)blockIdx.x + 1u) * (unsigned)TBLOCKS) >> 11);

  float acc = 0.0f;

  for (int t = t0; t < t1e; ++t) {
    int bi, bj; tile_coords(t, bi, bj);
    const int gi0 = bi*64, gj0 = bj*64;
    const bool full = (bi != bj);

    __syncthreads();                         // prev epilogue done with sT (also covers sPD stage)
    if (tid < 64)        sT2[tid]      = t2[gi0 + tid];
    else if (tid < 128)  sT1[tid - 64] = t1[gj0 + (tid - 64)];
    __syncthreads();

    const int Ra = (gi0 >> 4) + wr*2;
    const int Rb = (gj0 >> 4) + wc*2;
    f32x4 acc00 = {0.f,0.f,0.f,0.f}, acc01 = {0.f,0.f,0.f,0.f};
    f32x4 acc10 = {0.f,0.f,0.f,0.f}, acc11 = {0.f,0.f,0.f,0.f};
#pragma unroll
    for (int ks = 0; ks < 4; ++ks) {
      bf16x8 a0 = *reinterpret_cast<const bf16x8*>(x1b + ((((size_t)Ra    *4 + ks)*64 + lane) << 3));
      bf16x8 a1 = *reinterpret_cast<const bf16x8*>(x1b + ((((size_t)(Ra+1)*4 + ks)*64 + lane) << 3));
      bf16x8 b0 = *reinterpret_cast<const bf16x8*>(x2b + ((((size_t)Rb    *4 + ks)*64 + lane) << 3));
      bf16x8 b1 = *reinterpret_cast<const bf16x8*>(x2b + ((((size_t)(Rb+1)*4 + ks)*64 + lane) << 3));
      acc00 = __builtin_amdgcn_mfma_f32_16x16x32_bf16(a0, b0, acc00, 0, 0, 0);
      acc01 = __builtin_amdgcn_mfma_f32_16x16x32_bf16(a0, b1, acc01, 0, 0, 0);
      acc10 = __builtin_amdgcn_mfma_f32_16x16x32_bf16(a1, b0, acc10, 0, 0, 0);
      acc11 = __builtin_amdgcn_mfma_f32_16x16x32_bf16(a1, b1, acc11, 0, 0, 0);
    }

    float T2v[2][4], T1v[2];
#pragma unroll
    for (int tm = 0; tm < 2; ++tm)
#pragma unroll
      for (int rr = 0; rr < 4; ++rr) T2v[tm][rr] = sT2[wr*32 + tm*16 + rbase + rr];
    T1v[0] = sT1[wc*32 + fr];
    T1v[1] = sT1[wc*32 + 16 + fr];

    auto evalTile = [&](const f32x4& a, int tm, int tn) {
      const int lj = wc*32 + tn*16 + fr;
      const float t1v = T1v[tn];
#pragma unroll
      for (int rr = 0; rr < 4; ++rr) {
        const int li = wr*32 + tm*16 + rbase + rr;
        float s = a[rr];
        bool take = (full || (lj > li)) && (T2v[tm][rr] * t1v <= 0.0f);
        float uu = fmaf(s, 100.0f, 100.0f);
        int  idx = (int)uu;
        idx = idx < 0 ? 0 : (idx > NSTEPS-1 ? NSTEPS-1 : idx);
        float2 ab = sPD[idx];
        float contrib = fmaf(s, ab.y, ab.x);
        acc += take ? contrib : 0.0f;
      }
    };
    evalTile(acc00, 0, 0); evalTile(acc01, 0, 1);
    evalTile(acc10, 1, 0); evalTile(acc11, 1, 1);
  }

  // block reduction (once)
#pragma unroll
  for (int off = 32; off > 0; off >>= 1) acc += __shfl_xor(acc, off, 64);
  if (lane == 0) wsum[w] = acc;
  __syncthreads();
  if (tid == 0) {
    float s = wsum[0] + wsum[1] + wsum[2] + wsum[3];
    atomicAdd(&accbuf[blockIdx.x & 63], s);
  }
}

// ============ finalize ============
__global__ void finalize_kernel(const float* __restrict__ accbuf,
                                const float* __restrict__ np_in,
                                float* __restrict__ out)
{
  if (threadIdx.x == 0) {
    float s = 0.f;
    for (int c = 0; c < 64; ++c) s += accbuf[c];
    const float TOT = 33550336.0f;            // N*(N-1)/2
    float nn = fmaxf(TOT - np_in[0], 1.0f);
    out[0] = s / nn;
  }
}

extern "C" void kernel_launch(void* const* d_in, const int* in_sizes, int n_in,
                              void* d_out, int out_size, void* d_ws, size_t ws_size,
                              hipStream_t stream) {
  const float* x1 = (const float*)d_in[0];
  const float* x2 = (const float*)d_in[1];
  const float* t1 = (const float*)d_in[2];
  const float* t2 = (const float*)d_in[3];
  float* out = (float*)d_out;

  const size_t BF_BYTES = (size_t)N_EMB * D_EMB * sizeof(unsigned short);  // 2 MB each
  char* p = (char*)d_ws;
  unsigned short* x1b   = (unsigned short*)p;   p += BF_BYTES;
  unsigned short* x2b   = (unsigned short*)p;   p += BF_BYTES;
  float*          ghist = (float*)p;            p += (size_t)NZERO*sizeof(float);
  float*          accb  = (float*)p;            p += 64*sizeof(float);
  float2*         pd    = (float2*)p;           p += (size_t)NSTEPS*sizeof(float2);
  float*          np    = (float*)p;

  convert_kernel<<<(2*N_EMB*D_EMB/8 + 255)/256, 256, 0, stream>>>(x1, x2, x1b, x2b, ghist, accb);
  poshist_kernel<<<PGRID, 256, 0, stream>>>(x1b, x2b, t1, t2, ghist);
  cdf_kernel<<<1, 256, 0, stream>>>(ghist, pd, np);
  neginterp_kernel<<<PGRID, 256, 0, stream>>>(x1b, x2b, t1, t2, pd, accb);
  finalize_kernel<<<1, 64, 0, stream>>>(accb, np, out);
}

// Round 11
// 45.272 us; speedup vs baseline: 3.6679x; 1.6776x over previous
//
#include <hip/hip_runtime.h>

#define N_EMB   8192
#define D_EMB   128
#define NSTEPS  201
#define NB      128                  // 8192 / 64 tiles per dim
#define TBLOCKS (NB*(NB+1)/2)        // 8256 upper-tri tiles incl. diagonal
#define NCOPY   16                   // replicated global histogram copies
#define NHIST   16                   // per-quarter-wave LDS copies (per sign table)
#define PGRID   1536                 // persistent grid (6 blocks/CU, LDS-limited)

typedef __attribute__((ext_vector_type(8))) short bf16x8;
typedef __attribute__((ext_vector_type(4))) float f32x4;

// packed per-bin accumulator: (count << 21) | fq, fq = round(frac*1024)
#define CNT_SHIFT  21
#define FRAC_MASK  ((1u << CNT_SHIFT) - 1u)
#define NZERO      (NCOPY * 2 * NSTEPS)      // floats to zero in ghist

__device__ __forceinline__ unsigned short f2bf(float f) {
  unsigned int u = __builtin_bit_cast(unsigned int, f);
  u = (u + 0x7fffu + ((u >> 16) & 1u)) >> 16;   // RNE fp32 -> bf16
  return (unsigned short)u;
}

// ---- pre-pass: fp32 -> bf16 fragment-tiled; zeroes ghist (no memset) ----
__global__ __launch_bounds__(256) void convert_kernel(
    const float* __restrict__ x1, const float* __restrict__ x2,
    unsigned short* __restrict__ x1b, unsigned short* __restrict__ x2b,
    float* __restrict__ ghist)
{
  int t = blockIdx.x * 256 + threadIdx.x;
  if (t < NZERO) ghist[t] = 0.0f;
  const float*    src = (t < 131072) ? x1  : x2;
  unsigned short* dst = (t < 131072) ? x1b : x2b;
  int tt  = t & 131071;
  int r   = tt >> 4;
  int c16 = tt & 15;
  const float4* g = reinterpret_cast<const float4*>(src + ((size_t)r << 7) + c16*8);
  float4 v0 = g[0], v1 = g[1];
  int R = r >> 4, fr = r & 15, K = c16 >> 2, kg = c16 & 3;
  size_t chunk = ((size_t)(R*4 + K) << 6) + (size_t)(kg*16 + fr);
  uint4 p;
  p.x = f2bf(v0.x) | ((unsigned int)f2bf(v0.y) << 16);
  p.y = f2bf(v0.z) | ((unsigned int)f2bf(v0.w) << 16);
  p.z = f2bf(v1.x) | ((unsigned int)f2bf(v1.y) << 16);
  p.w = f2bf(v1.z) | ((unsigned int)f2bf(v1.w) << 16);
  *reinterpret_cast<uint4*>(dst + chunk*8) = p;
}

// ============ main pass: both histograms, persistent, strip-major with B-frag cache ============
__global__ __launch_bounds__(256, 6) void main_kernel(
    const unsigned short* __restrict__ x1b, const unsigned short* __restrict__ x2b,
    const float* __restrict__ t1g, const float* __restrict__ t2g,
    float* __restrict__ ghist)
{
  __shared__ unsigned int whist[2][NHIST][NSTEPS];   // [pos/neg][copy][bin]

  const int tid = threadIdx.x;
  for (int b = tid; b < 2*NHIST*NSTEPS; b += 256) ((unsigned int*)whist)[b] = 0u;

  const int lane = tid & 63;
  const int w    = tid >> 6;
  const int wr   = w >> 1, wc = w & 1;
  const int fr   = lane & 15;
  const int kg   = lane >> 4;
  const int rbase = kg * 4;
  unsigned int* whP = &whist[0][(w << 2) | kg][0];
  const int NEGOFF = NHIST * NSTEPS;          // element offset pos-table -> neg-table

  // persistent range: tiles [bid*43/8, (bid+1)*43/8)  (8256/1536 = 43/8)
  const int t0  = (int)(((unsigned)blockIdx.x      * 43u) >> 3);
  const int t1e = (int)(((unsigned)(blockIdx.x+1u) * 43u) >> 3);

  __syncthreads();                            // whist zeroing visible

  int prev_bj = -1;
  bf16x8 bQ[2][4];                            // cached B frags [n-tile][ks] (32 VGPR)
  float  T1v[2];

  for (int t = t0; t < t1e; ++t) {
    // strip-major coords: bj = strip, bi = t - bj(bj+1)/2, bi <= bj
    int j = (int)((sqrtf(8.0f*(float)t + 1.0f) - 1.0f) * 0.5f);
    while ((j+1)*(j+2)/2 <= t) ++j;
    while (j*(j+1)/2 > t) --j;
    const int bi = t - j*(j+1)/2;
    const int gi0 = bi*64, gj0 = j*64;
    const bool full = (bi != j);

    if (j != prev_bj) {                       // strip crossing: reload B frags + T1 (wave-uniform)
      prev_bj = j;
      const int Rb = (gj0 >> 4) + wc*2;
#pragma unroll
      for (int ks = 0; ks < 4; ++ks) {
        bQ[0][ks] = *reinterpret_cast<const bf16x8*>(x2b + ((((size_t)Rb    *4 + ks)*64 + lane) << 3));
        bQ[1][ks] = *reinterpret_cast<const bf16x8*>(x2b + ((((size_t)(Rb+1)*4 + ks)*64 + lane) << 3));
      }
      T1v[0] = t1g[gj0 + wc*32 + fr];
      T1v[1] = t1g[gj0 + wc*32 + 16 + fr];
    }

    const int Ra = (gi0 >> 4) + wr*2;
    f32x4 acc00 = {0.f,0.f,0.f,0.f}, acc01 = {0.f,0.f,0.f,0.f};
    f32x4 acc10 = {0.f,0.f,0.f,0.f}, acc11 = {0.f,0.f,0.f,0.f};
#pragma unroll
    for (int ks = 0; ks < 4; ++ks) {
      bf16x8 a0 = *reinterpret_cast<const bf16x8*>(x1b + ((((size_t)Ra    *4 + ks)*64 + lane) << 3));
      bf16x8 a1 = *reinterpret_cast<const bf16x8*>(x1b + ((((size_t)(Ra+1)*4 + ks)*64 + lane) << 3));
      acc00 = __builtin_amdgcn_mfma_f32_16x16x32_bf16(a0, bQ[0][ks], acc00, 0, 0, 0);
      acc01 = __builtin_amdgcn_mfma_f32_16x16x32_bf16(a0, bQ[1][ks], acc01, 0, 0, 0);
      acc10 = __builtin_amdgcn_mfma_f32_16x16x32_bf16(a1, bQ[0][ks], acc10, 0, 0, 0);
      acc11 = __builtin_amdgcn_mfma_f32_16x16x32_bf16(a1, bQ[1][ks], acc11, 0, 0, 0);
    }

    // row targets from global (L1/L2-resident; 16 lanes share each address)
    float T2v[2][4];
#pragma unroll
    for (int tm = 0; tm < 2; ++tm)
#pragma unroll
      for (int rr = 0; rr < 4; ++rr) T2v[tm][rr] = t2g[gi0 + wr*32 + tm*16 + rbase + rr];

    // C/D layout (m89/m91): col = lane&15, row = (lane>>4)*4 + reg
    auto dep = [&](const f32x4& a, int tm, int tn) {
      const int lj = wc*32 + tn*16 + fr;
      const float t1v = T1v[tn];
#pragma unroll
      for (int rr = 0; rr < 4; ++rr) {
        const int li = wr*32 + tm*16 + rbase + rr;
        bool pos = (T2v[tm][rr] * t1v > 0.0f);
        float uu = fmaf(a[rr], 102400.0f, 102400.5f);
        int   iu = (int)uu;
        int  idx = iu >> 10;
        idx = idx < 0 ? 0 : (idx > NSTEPS-1 ? NSTEPS-1 : idx);
        unsigned int pk = (1u << CNT_SHIFT) | (unsigned int)(iu & 1023);
        unsigned int* dst = whP + (pos ? 0 : NEGOFF) + idx;
        if (full || (lj > li)) atomicAdd(dst, pk);
      }
    };
    dep(acc00, 0, 0); dep(acc01, 0, 1);
    dep(acc10, 1, 0); dep(acc11, 1, 1);
  }
  __syncthreads();

  // unpack + flush once per sign table:
  // h[b] = cnt[b] - fr[b]/1024 + fr[b-1]/1024 ; h[200] = cnt[200] + fr[199]/1024
  float* gh = ghist + (size_t)(blockIdx.x & (NCOPY-1)) * (2*NSTEPS);
  if (tid < NSTEPS) {
    const int b = tid;
    const float inv = 1.0f / 1024.0f;
#pragma unroll
    for (int sg = 0; sg < 2; ++sg) {
      unsigned int cp = 0; float fp = 0.f, fpm1 = 0.f;
#pragma unroll
      for (int ww = 0; ww < NHIST; ++ww) {
        unsigned int vp = whist[sg][ww][b];
        cp += vp >> CNT_SHIFT;  fp += (float)(vp & FRAC_MASK);
        if (b > 0) fpm1 += (float)(whist[sg][ww][b-1] & FRAC_MASK);
      }
      float hv = (b == NSTEPS-1) ? ((float)cp + fpm1 * inv)
                                 : ((float)cp - fp * inv + fpm1 * inv);
      if (hv != 0.0f) atomicAdd(&gh[sg*NSTEPS + b], hv);
    }
  }
}

// ============ finalize: sum copies, cumsum pos, dot with neg ============
__global__ void finalize_kernel(const float* __restrict__ ghist,
                                float* __restrict__ out)
{
  __shared__ float hp[NSTEPS], hn[NSTEPS];
  const int tid = threadIdx.x;
  if (tid < NSTEPS) {
    float sp = 0.f, sn = 0.f;
#pragma unroll
    for (int c = 0; c < NCOPY; ++c) {
      sp += ghist[(size_t)c*(2*NSTEPS) + tid];
      sn += ghist[(size_t)c*(2*NSTEPS) + NSTEPS + tid];
    }
    hp[tid] = sp; hn[tid] = sn;
  }
  __syncthreads();
  if (tid == 0) {
    const float TOT = 33550336.0f;            // N*(N-1)/2
    float np = 0.f;
    for (int b = 0; b < NSTEPS; ++b) np += hp[b];
    float nn = TOT - np;
    float ip  = 1.0f / fmaxf(np, 1.0f);
    float in_ = 1.0f / fmaxf(nn, 1.0f);
    float cdf = 0.f, loss = 0.f;
    for (int b = 0; b < NSTEPS; ++b) {
      cdf  += hp[b] * ip;
      loss += hn[b] * in_ * cdf;
    }
    out[0] = loss;
  }
}

extern "C" void kernel_launch(void* const* d_in, const int* in_sizes, int n_in,
                              void* d_out, int out_size, void* d_ws, size_t ws_size,
                              hipStream_t stream) {
  const float* x1 = (const float*)d_in[0];
  const float* x2 = (const float*)d_in[1];
  const float* t1 = (const float*)d_in[2];
  const float* t2 = (const float*)d_in[3];
  float* out = (float*)d_out;

  const size_t BF_BYTES = (size_t)N_EMB * D_EMB * sizeof(unsigned short);  // 2 MB each
  char* p = (char*)d_ws;
  unsigned short* x1b   = (unsigned short*)p;   p += BF_BYTES;
  unsigned short* x2b   = (unsigned short*)p;   p += BF_BYTES;
  float*          ghist = (float*)p;

  convert_kernel<<<(2*N_EMB*D_EMB/8 + 255)/256, 256, 0, stream>>>(x1, x2, x1b, x2b, ghist);
  main_kernel<<<PGRID, 256, 0, stream>>>(x1b, x2b, t1, t2, ghist);
  finalize_kernel<<<1, 256, 0, stream>>>(ghist, out);
}